// Round 5
// baseline (205.362 us; speedup 1.0000x reference)
//
#include <hip/hip_runtime.h>

#define DIM 160
#define PLANE 25600          // 160*160
#define NVOX 4096000         // 160^3
constexpr float INV_WS = 1.0f / 729.0f;

#define TW 32                // output tile width  (W)
#define TH 16                // output tile height (H)
#define DC 16                // output depth chunk (D)
#define HW 40                // TW+8 halo width
#define HH 24                // TH+8 halo height
#define PSTR 41              // prod row stride
#define WSTR 33              // wsum/hcol row stride

#define NCC_WAVES 4000       // 500 blocks * 8 waves
#define GRAD_WAVES 1200      // 300 blocks * 4 waves

// ---------------------------------------------------------------------------
// Fused NCC, 3-stage sliding separable box sum per D-slice:
//   prod(LDS) -> W-slide (240 tasks: 24 reads -> 16 outs)
//             -> H-slide (160 tasks: 24 reads -> 16 outs)
//             -> final read (5 b32/thread) -> D-ring (regs) -> cc.
// 512 threads (8 waves), grid (5,10,10). LDS 46 KB.
// ---------------------------------------------------------------------------
__global__ __launch_bounds__(512)
void ncc_fused_kernel(const float* __restrict__ I, const float* __restrict__ J,
                      double* __restrict__ part) {
    __shared__ float prod[5][HH * PSTR];   // 19.7 KB
    __shared__ float wsum[5][HH * WSTR];   // 15.8 KB (24 rows x 32 used cols)
    __shared__ float hcol[5][TH * WSTR];   // 10.6 KB (16 rows x 32 used cols)

    const int tid = threadIdx.x;
    const int w0 = blockIdx.x * TW;
    const int h0 = blockIdx.y * TH;
    const int d0 = blockIdx.z * DC;
    const int wi = tid & 31;       // output col
    const int hi = tid >> 5;       // output row (0..15)

    // --- halo load decode (960 positions, 2 per thread) ---
    const int r0 = tid / HW, c0 = tid - r0 * HW;
    const int p1 = tid + 512;
    const int r1 = p1 / HW, c1 = p1 - r1 * HW;
    const int gr0 = h0 - 4 + r0, gc0 = w0 - 4 + c0;
    const int gr1 = h0 - 4 + r1, gc1 = w0 - 4 + c1;
    const bool v0 = (gr0 >= 0 && gr0 < DIM && gc0 >= 0 && gc0 < DIM);
    const bool v1 = (p1 < HH * HW) && (gr1 >= 0 && gr1 < DIM && gc1 >= 0 && gc1 < DIM);
    const int off0 = gr0 * DIM + gc0;
    const int off1 = gr1 * DIM + gc1;

    // --- W-slide task decode: 240 = 5f x 24row x 2half ---
    const int wt_f    = tid / 48;            // field (valid for tid<240)
    const int wt_rem  = tid - wt_f * 48;
    const int wt_r    = wt_rem >> 1;         // halo row 0..23
    const int wt_base = (wt_rem & 1) * 16;   // output col base 0|16

    // --- H-slide task decode: 160 = 5f x 32col ---
    const int ht_f = tid >> 5;               // field (valid for tid<160)
    const int ht_w = tid & 31;               // col

    float S[5][9];                           // D-ring (static slots only)
    #pragma unroll
    for (int f = 0; f < 5; ++f)
        #pragma unroll
        for (int s = 0; s < 9; ++s) S[f][s] = 0.f;
    float R[5] = {0.f, 0.f, 0.f, 0.f, 0.f};
    float local = 0.f;

    for (int k0 = 0; k0 < DC + 8; k0 += 9) {   // slot j is compile-time static
        #pragma unroll
        for (int j = 0; j < 9; ++j) {
            const int k = k0 + j;
            if (k < DC + 8) {
                const int ds = d0 - 4 + k;
                if (ds >= 0 && ds < DIM) {     // block-uniform branch
                    const int sb = ds * PLANE;
                    // stage 0: products into LDS
                    {
                        float a = 0.f, b = 0.f;
                        if (v0) { a = I[sb + off0]; b = J[sb + off0]; }
                        const int o = r0 * PSTR + c0;
                        prod[0][o] = a; prod[1][o] = b;
                        prod[2][o] = a * a; prod[3][o] = b * b; prod[4][o] = a * b;
                        if (p1 < HH * HW) {
                            float a1 = 0.f, b1 = 0.f;
                            if (v1) { a1 = I[sb + off1]; b1 = J[sb + off1]; }
                            const int o1 = r1 * PSTR + c1;
                            prod[0][o1] = a1; prod[1][o1] = b1;
                            prod[2][o1] = a1 * a1; prod[3][o1] = b1 * b1; prod[4][o1] = a1 * b1;
                        }
                    }
                    __syncthreads();
                    // stage 1: W-slide, 9-tap along W
                    if (tid < 240) {
                        float c[24];
                        #pragma unroll
                        for (int q = 0; q < 24; ++q)
                            c[q] = prod[wt_f][wt_r * PSTR + wt_base + q];
                        float s = c[0]+c[1]+c[2]+c[3]+c[4]+c[5]+c[6]+c[7]+c[8];
                        wsum[wt_f][wt_r * WSTR + wt_base] = s;
                        #pragma unroll
                        for (int q = 1; q < 16; ++q) {
                            s += c[q + 8] - c[q - 1];
                            wsum[wt_f][wt_r * WSTR + wt_base + q] = s;
                        }
                    }
                    __syncthreads();
                    // stage 2: H-slide, 9-tap along H (down columns)
                    if (tid < 160) {
                        float c[24];
                        #pragma unroll
                        for (int q = 0; q < 24; ++q)
                            c[q] = wsum[ht_f][q * WSTR + ht_w];
                        float s = c[0]+c[1]+c[2]+c[3]+c[4]+c[5]+c[6]+c[7]+c[8];
                        hcol[ht_f][ht_w] = s;
                        #pragma unroll
                        for (int q = 1; q < 16; ++q) {
                            s += c[q + 8] - c[q - 1];
                            hcol[ht_f][q * WSTR + ht_w] = s;
                        }
                    }
                    __syncthreads();
                    // stage 3: ring + running sums (5 reads/thread)
                    #pragma unroll
                    for (int f = 0; f < 5; ++f) {
                        float P = hcol[f][hi * WSTR + wi];
                        R[f] += P - S[f][j];
                        S[f][j] = P;
                    }
                } else {
                    #pragma unroll
                    for (int f = 0; f < 5; ++f) { R[f] -= S[f][j]; S[f][j] = 0.f; }
                }
                if (k >= 8) {
                    float cross = R[4] - R[0] * R[1] * INV_WS;
                    float Iv    = R[2] - R[0] * R[0] * INV_WS;
                    float Jv    = R[3] - R[1] * R[1] * INV_WS;
                    local += cross * cross / (Iv * Jv + 1e-5f);
                }
            }
        }
    }

    for (int off = 32; off; off >>= 1) local += __shfl_down(local, off);
    if ((tid & 63) == 0) {
        int wave = ((blockIdx.z * gridDim.y + blockIdx.y) * gridDim.x + blockIdx.x) * 8
                 + (tid >> 6);
        part[wave] = (double)local;
    }
}

// ---------------------------------------------------------------------------
// Gradient loss: thread owns (h, w4-lane), walks a 40-slice D chunk.
// d-neighbor = previous iteration's register; h-neighbor = L1 hit.
// grid (5, 5, 12): x -> w4 group, y -> h group, z -> channel*4 + d-chunk.
// ---------------------------------------------------------------------------
__global__ void grad_kernel(const float* __restrict__ s, double* __restrict__ part) {
    const int Q = NVOX / 4;
    const float4* s4 = (const float4*)s;
    const int w4 = blockIdx.x * 8 + (threadIdx.x & 7);     // 0..39
    const int h  = blockIdx.y * 32 + (threadIdx.x >> 3);   // 0..159
    const int c  = blockIdx.z >> 2;
    const int d0 = (blockIdx.z & 3) * 40;
    const int qbase = c * Q + h * (DIM / 4) + w4;

    float local = 0.f;
    float4 v = s4[qbase + d0 * (PLANE / 4)];
    for (int step = 0; step < 40; ++step) {
        const int d = d0 + step;
        const int qi = qbase + d * (PLANE / 4);
        float t;
        // W diffs (within float4 + cross-lane scalar)
        t = v.y - v.x; local += t * t;
        t = v.z - v.y; local += t * t;
        t = v.w - v.z; local += t * t;
        if (w4 < DIM / 4 - 1) {
            float nx = s[(qi + 1) * 4];
            t = nx - v.w; local += t * t;
        }
        // H diff
        if (h < DIM - 1) {
            float4 vh = s4[qi + DIM / 4];
            t = vh.x - v.x; local += t * t;
            t = vh.y - v.y; local += t * t;
            t = vh.z - v.z; local += t * t;
            t = vh.w - v.w; local += t * t;
        }
        // D diff (register reuse)
        if (d < DIM - 1) {
            float4 vn = s4[qi + PLANE / 4];
            t = vn.x - v.x; local += t * t;
            t = vn.y - v.y; local += t * t;
            t = vn.z - v.z; local += t * t;
            t = vn.w - v.w; local += t * t;
            v = vn;
        }
    }

    for (int off = 32; off; off >>= 1) local += __shfl_down(local, off);
    if ((threadIdx.x & 63) == 0) {
        int linear = (blockIdx.z * gridDim.y + blockIdx.y) * gridDim.x + blockIdx.x;
        part[NCC_WAVES + linear * 4 + (threadIdx.x >> 6)] = (double)local;
    }
}

// ---------------------------------------------------------------------------
// Final combine.
// ---------------------------------------------------------------------------
__global__ void final_kernel(const double* __restrict__ part, float* __restrict__ out) {
    __shared__ double s_n[4], s_g[4];
    double n = 0.0, g = 0.0;
    for (int i = threadIdx.x; i < NCC_WAVES; i += 256) n += part[i];
    for (int i = threadIdx.x; i < GRAD_WAVES; i += 256) g += part[NCC_WAVES + i];
    for (int off = 32; off; off >>= 1) {
        n += __shfl_down(n, off);
        g += __shfl_down(g, off);
    }
    if ((threadIdx.x & 63) == 0) {
        s_n[threadIdx.x >> 6] = n;
        s_g[threadIdx.x >> 6] = g;
    }
    __syncthreads();
    if (threadIdx.x == 0) {
        double ncc_sum  = s_n[0] + s_n[1] + s_n[2] + s_n[3];
        double grad_sum = s_g[0] + s_g[1] + s_g[2] + s_g[3];
        double ncc  = -(ncc_sum / 4096000.0);
        double grad = grad_sum / 36633600.0;   // sum / (3*159*160*160) / 3
        double loss = 10.0 * ncc + 15.0 * grad;
        out[0] = (float)loss;
        out[1] = (float)ncc;
        out[2] = (float)grad;
    }
}

extern "C" void kernel_launch(void* const* d_in, const int* in_sizes, int n_in,
                              void* d_out, int out_size, void* d_ws, size_t ws_size,
                              hipStream_t stream) {
    const float* y    = (const float*)d_in[0];
    const float* tgt  = (const float*)d_in[1];
    // d_in[2] = src, unused by the reference
    const float* flow = (const float*)d_in[3];
    float* out = (float*)d_out;
    double* part = (double*)d_ws;   // every slot written every call

    dim3 g1(DIM / TW, DIM / TH, DIM / DC);   // (5, 10, 10)
    ncc_fused_kernel<<<g1, 512, 0, stream>>>(tgt, y, part);
    dim3 g2(5, 5, 12);
    grad_kernel<<<g2, 256, 0, stream>>>(flow, part);
    final_kernel<<<1, 256, 0, stream>>>(part, out);
}

// Round 9
// 179.183 us; speedup vs baseline: 1.1461x; 1.1461x over previous
//
#include <hip/hip_runtime.h>

#define DIM 160
#define PLANE 25600          // 160*160
#define NVOX 4096000         // 160^3
constexpr float INV_WS = 1.0f / 729.0f;

#define TW 32                // output tile width  (W)
#define TH 16                // output tile height (H)
#define DC 16                // output depth chunk (D)
#define HW 40                // TW+8 halo width
#define HH 24                // TH+8 halo height
#define PSTR 41              // prod row stride
#define WSTR 33              // wsum/hcol row stride

#define NCC_BLOCKS 500       // 5 x 10 x 10 tiles
#define GRAD_BLOCKS 500
#define NCC_WAVES 4000       // 500 blocks * 8 waves
#define GRAD_WAVES 4000      // 500 blocks * 8 waves

// ---------------------------------------------------------------------------
// Unified kernel: blocks [0,500) do NCC tiles (LDS/VALU-bound); blocks
// [500,1000) do the flow-gradient stream (memory-bound). Heterogeneous
// blocks co-resident on each CU overlap the two regimes.
// LDS: hcol aliases the (dead-by-then) prod buffer -> 35.4 KB -> 4 blk/CU.
// ---------------------------------------------------------------------------
__global__ __launch_bounds__(512)
void fused_kernel(const float* __restrict__ I, const float* __restrict__ J,
                  const float* __restrict__ flow, double* __restrict__ part) {
    __shared__ float prodA[5][HH * PSTR];   // 19.7 KB (stage0..1), hcol alias after
    __shared__ float wsum[5][HH * WSTR];    // 15.8 KB
    float (*hcol)[TH * WSTR] = (float (*)[TH * WSTR]) & prodA[0][0];  // 10.6 KB alias

    const int tid = threadIdx.x;

    if (blockIdx.x < NCC_BLOCKS) {
        // =================== NCC tile ===================
        const int b  = blockIdx.x;
        const int bx = b % 5;
        const int by = (b / 5) % 10;
        const int bz = b / 50;
        const int w0 = bx * TW;
        const int h0 = by * TH;
        const int d0 = bz * DC;
        const int wi = tid & 31;
        const int hi = tid >> 5;

        // halo load decode (960 positions, 2 per thread)
        const int r0 = tid / HW, c0 = tid - r0 * HW;
        const int p1 = tid + 512;
        const int r1 = p1 / HW, c1 = p1 - r1 * HW;
        const int gr0 = h0 - 4 + r0, gc0 = w0 - 4 + c0;
        const int gr1 = h0 - 4 + r1, gc1 = w0 - 4 + c1;
        const bool v0 = (gr0 >= 0 && gr0 < DIM && gc0 >= 0 && gc0 < DIM);
        const bool v1 = (p1 < HH * HW) && (gr1 >= 0 && gr1 < DIM && gc1 >= 0 && gc1 < DIM);
        const int off0 = gr0 * DIM + gc0;
        const int off1 = gr1 * DIM + gc1;

        // W-slide tasks: 240 = 5f x 24row x 2half
        const int wt_f    = tid / 48;
        const int wt_rem  = tid - wt_f * 48;
        const int wt_r    = wt_rem >> 1;
        const int wt_base = (wt_rem & 1) * 16;

        // H-slide tasks: 160 = 5f x 32col
        const int ht_f = tid >> 5;
        const int ht_w = tid & 31;

        float S[5][9];
        #pragma unroll
        for (int f = 0; f < 5; ++f)
            #pragma unroll
            for (int s = 0; s < 9; ++s) S[f][s] = 0.f;
        float R[5] = {0.f, 0.f, 0.f, 0.f, 0.f};
        float local = 0.f;

        for (int k0 = 0; k0 < DC + 8; k0 += 9) {   // slot j stays compile-time
            #pragma unroll
            for (int j = 0; j < 9; ++j) {
                const int k = k0 + j;
                if (k < DC + 8) {
                    const int ds = d0 - 4 + k;
                    if (ds >= 0 && ds < DIM) {     // block-uniform
                        const int sb = ds * PLANE;
                        __syncthreads();   // hcol(alias) reads done before prod write
                        // stage 0: products
                        {
                            float a = 0.f, bb = 0.f;
                            if (v0) { a = I[sb + off0]; bb = J[sb + off0]; }
                            const int o = r0 * PSTR + c0;
                            prodA[0][o] = a; prodA[1][o] = bb;
                            prodA[2][o] = a * a; prodA[3][o] = bb * bb; prodA[4][o] = a * bb;
                            if (p1 < HH * HW) {
                                float a1 = 0.f, b1 = 0.f;
                                if (v1) { a1 = I[sb + off1]; b1 = J[sb + off1]; }
                                const int o1 = r1 * PSTR + c1;
                                prodA[0][o1] = a1; prodA[1][o1] = b1;
                                prodA[2][o1] = a1 * a1; prodA[3][o1] = b1 * b1; prodA[4][o1] = a1 * b1;
                            }
                        }
                        __syncthreads();
                        // stage 1: W-slide
                        if (tid < 240) {
                            float c[24];
                            #pragma unroll
                            for (int q = 0; q < 24; ++q)
                                c[q] = prodA[wt_f][wt_r * PSTR + wt_base + q];
                            float s = c[0]+c[1]+c[2]+c[3]+c[4]+c[5]+c[6]+c[7]+c[8];
                            wsum[wt_f][wt_r * WSTR + wt_base] = s;
                            #pragma unroll
                            for (int q = 1; q < 16; ++q) {
                                s += c[q + 8] - c[q - 1];
                                wsum[wt_f][wt_r * WSTR + wt_base + q] = s;
                            }
                        }
                        __syncthreads();
                        // stage 2: H-slide (writes hcol = prod alias; prod is dead)
                        if (tid < 160) {
                            float c[24];
                            #pragma unroll
                            for (int q = 0; q < 24; ++q)
                                c[q] = wsum[ht_f][q * WSTR + ht_w];
                            float s = c[0]+c[1]+c[2]+c[3]+c[4]+c[5]+c[6]+c[7]+c[8];
                            hcol[ht_f][ht_w] = s;
                            #pragma unroll
                            for (int q = 1; q < 16; ++q) {
                                s += c[q + 8] - c[q - 1];
                                hcol[ht_f][q * WSTR + ht_w] = s;
                            }
                        }
                        __syncthreads();
                        // stage 3: ring + running sums
                        #pragma unroll
                        for (int f = 0; f < 5; ++f) {
                            float P = hcol[f][hi * WSTR + wi];
                            R[f] += P - S[f][j];
                            S[f][j] = P;
                        }
                    } else {
                        #pragma unroll
                        for (int f = 0; f < 5; ++f) { R[f] -= S[f][j]; S[f][j] = 0.f; }
                    }
                    if (k >= 8) {
                        float cross = R[4] - R[0] * R[1] * INV_WS;
                        float Iv    = R[2] - R[0] * R[0] * INV_WS;
                        float Jv    = R[3] - R[1] * R[1] * INV_WS;
                        local += cross * cross / (Iv * Jv + 1e-5f);
                    }
                }
            }
        }

        for (int off = 32; off; off >>= 1) local += __shfl_down(local, off);
        if ((tid & 63) == 0) {
            part[b * 8 + (tid >> 6)] = (double)local;
        }
    } else {
        // =================== flow gradient ===================
        const int Q = NVOX / 4;                       // float4s per channel
        const float4* s4 = (const float4*)flow;
        const int gb = blockIdx.x - NCC_BLOCKS;
        float local = 0.f;
        for (int i = gb * 512 + tid; i < 3 * Q; i += GRAD_BLOCKS * 512) {
            int c    = i / Q;
            int rem  = i - c * Q;
            int w4   = rem % (DIM / 4);
            int rest = rem / (DIM / 4);
            int h = rest % DIM;
            int d = rest / DIM;
            float4 v = s4[i];
            float t;
            t = v.y - v.x; local += t * t;
            t = v.z - v.y; local += t * t;
            t = v.w - v.z; local += t * t;
            if (w4 < DIM / 4 - 1) {
                float nx = flow[i * 4 + 4];
                t = nx - v.w; local += t * t;
            }
            if (h < DIM - 1) {
                float4 vh = s4[i + DIM / 4];
                t = vh.x - v.x; local += t * t;
                t = vh.y - v.y; local += t * t;
                t = vh.z - v.z; local += t * t;
                t = vh.w - v.w; local += t * t;
            }
            if (d < DIM - 1) {
                float4 vd = s4[i + PLANE / 4];
                t = vd.x - v.x; local += t * t;
                t = vd.y - v.y; local += t * t;
                t = vd.z - v.z; local += t * t;
                t = vd.w - v.w; local += t * t;
            }
        }
        for (int off = 32; off; off >>= 1) local += __shfl_down(local, off);
        if ((tid & 63) == 0) {
            part[NCC_WAVES + gb * 8 + (tid >> 6)] = (double)local;
        }
    }
}

// ---------------------------------------------------------------------------
// Final combine.
// ---------------------------------------------------------------------------
__global__ void final_kernel(const double* __restrict__ part, float* __restrict__ out) {
    __shared__ double s_n[4], s_g[4];
    double n = 0.0, g = 0.0;
    for (int i = threadIdx.x; i < NCC_WAVES; i += 256) n += part[i];
    for (int i = threadIdx.x; i < GRAD_WAVES; i += 256) g += part[NCC_WAVES + i];
    for (int off = 32; off; off >>= 1) {
        n += __shfl_down(n, off);
        g += __shfl_down(g, off);
    }
    if ((threadIdx.x & 63) == 0) {
        s_n[threadIdx.x >> 6] = n;
        s_g[threadIdx.x >> 6] = g;
    }
    __syncthreads();
    if (threadIdx.x == 0) {
        double ncc_sum  = s_n[0] + s_n[1] + s_n[2] + s_n[3];
        double grad_sum = s_g[0] + s_g[1] + s_g[2] + s_g[3];
        double ncc  = -(ncc_sum / 4096000.0);
        double grad = grad_sum / 36633600.0;   // sum / (3*159*160*160) / 3
        double loss = 10.0 * ncc + 15.0 * grad;
        out[0] = (float)loss;
        out[1] = (float)ncc;
        out[2] = (float)grad;
    }
}

extern "C" void kernel_launch(void* const* d_in, const int* in_sizes, int n_in,
                              void* d_out, int out_size, void* d_ws, size_t ws_size,
                              hipStream_t stream) {
    const float* y    = (const float*)d_in[0];
    const float* tgt  = (const float*)d_in[1];
    // d_in[2] = src, unused by the reference
    const float* flow = (const float*)d_in[3];
    float* out = (float*)d_out;
    double* part = (double*)d_ws;   // every slot written every call

    fused_kernel<<<NCC_BLOCKS + GRAD_BLOCKS, 512, 0, stream>>>(tgt, y, flow, part);
    final_kernel<<<1, 256, 0, stream>>>(part, out);
}

// Round 10
// 171.611 us; speedup vs baseline: 1.1967x; 1.0441x over previous
//
#include <hip/hip_runtime.h>

#define DIM 160
#define PLANE 25600          // 160*160
#define NVOX 4096000         // 160^3
constexpr float INV_WS = 1.0f / 729.0f;

#define TW 32                // output tile width  (W)
#define TH 16                // output tile height (H)
#define DC 16                // output depth chunk (D)
#define HW 40                // TW+8 halo width
#define HH 24                // TH+8 halo height
#define PSTR 41              // prod row stride
#define WSTR 33              // wsum/hcol row stride

#define NCC_PARTS 500        // 5 x 10 x 10 blocks, 1 partial each
#define GRAD_PARTS 1024

// ---------------------------------------------------------------------------
// NCC: 3-stage sliding separable box sum per D-slice (R5 structure, measured
// ~44 us). 512 threads, grid (5,10,10), LDS 46 KB, 3 barriers/slice.
// Task rebalance vs R5: W-slide 480 tasks x 8 outs, H-slide 320 tasks x 8 outs.
// ---------------------------------------------------------------------------
__global__ __launch_bounds__(512)
void ncc_kernel(const float* __restrict__ I, const float* __restrict__ J,
                double* __restrict__ part) {
    __shared__ float prod[5][HH * PSTR];   // 19.7 KB
    __shared__ float wsum[5][HH * WSTR];   // 15.8 KB
    __shared__ float hcol[5][TH * WSTR];   // 10.6 KB
    __shared__ double s_p[8];

    const int tid = threadIdx.x;
    const int w0 = blockIdx.x * TW;
    const int h0 = blockIdx.y * TH;
    const int d0 = blockIdx.z * DC;
    const int wi = tid & 31;       // output col
    const int hi = tid >> 5;       // output row (0..15)

    // --- halo load decode (960 positions, 2 per thread) ---
    const int r0 = tid / HW, c0 = tid - r0 * HW;
    const int p1 = tid + 512;
    const int r1 = p1 / HW, c1 = p1 - r1 * HW;
    const int gr0 = h0 - 4 + r0, gc0 = w0 - 4 + c0;
    const int gr1 = h0 - 4 + r1, gc1 = w0 - 4 + c1;
    const bool v0 = (gr0 >= 0 && gr0 < DIM && gc0 >= 0 && gc0 < DIM);
    const bool v1 = (p1 < HH * HW) && (gr1 >= 0 && gr1 < DIM && gc1 >= 0 && gc1 < DIM);
    const int off0 = gr0 * DIM + gc0;
    const int off1 = gr1 * DIM + gc1;

    // --- W-slide tasks: 480 = 5f x 24row x 4seg; 16 reads -> 8 outs ---
    const int wt_f    = tid / 96;            // field (valid for tid<480)
    const int wt_rem  = tid - wt_f * 96;
    const int wt_r    = wt_rem >> 2;         // halo row 0..23
    const int wt_base = (wt_rem & 3) * 8;    // output col base 0|8|16|24

    // --- H-slide tasks: 320 = 5f x 32col x 2half; 16 reads -> 8 outs ---
    const int ht_f    = tid / 64;            // field (valid for tid<320)
    const int ht_rem  = tid - ht_f * 64;
    const int ht_w    = ht_rem & 31;         // col
    const int ht_base = (ht_rem >> 5) * 8;   // output row base 0|8

    float S[5][9];                           // D-ring (static slots only)
    #pragma unroll
    for (int f = 0; f < 5; ++f)
        #pragma unroll
        for (int s = 0; s < 9; ++s) S[f][s] = 0.f;
    float R[5] = {0.f, 0.f, 0.f, 0.f, 0.f};
    float local = 0.f;

    for (int k0 = 0; k0 < DC + 8; k0 += 9) {   // slot j is compile-time static
        #pragma unroll
        for (int j = 0; j < 9; ++j) {
            const int k = k0 + j;
            if (k < DC + 8) {
                const int ds = d0 - 4 + k;
                if (ds >= 0 && ds < DIM) {     // block-uniform branch
                    const int sb = ds * PLANE;
                    // stage 0: products into LDS
                    {
                        float a = 0.f, b = 0.f;
                        if (v0) { a = I[sb + off0]; b = J[sb + off0]; }
                        const int o = r0 * PSTR + c0;
                        prod[0][o] = a; prod[1][o] = b;
                        prod[2][o] = a * a; prod[3][o] = b * b; prod[4][o] = a * b;
                        if (p1 < HH * HW) {
                            float a1 = 0.f, b1 = 0.f;
                            if (v1) { a1 = I[sb + off1]; b1 = J[sb + off1]; }
                            const int o1 = r1 * PSTR + c1;
                            prod[0][o1] = a1; prod[1][o1] = b1;
                            prod[2][o1] = a1 * a1; prod[3][o1] = b1 * b1; prod[4][o1] = a1 * b1;
                        }
                    }
                    __syncthreads();
                    // stage 1: W-slide, 9-tap along W (480 tasks, 8 outs each)
                    if (tid < 480) {
                        float c[16];
                        #pragma unroll
                        for (int q = 0; q < 16; ++q)
                            c[q] = prod[wt_f][wt_r * PSTR + wt_base + q];
                        float s = c[0]+c[1]+c[2]+c[3]+c[4]+c[5]+c[6]+c[7]+c[8];
                        wsum[wt_f][wt_r * WSTR + wt_base] = s;
                        #pragma unroll
                        for (int q = 1; q < 8; ++q) {
                            s += c[q + 8] - c[q - 1];
                            wsum[wt_f][wt_r * WSTR + wt_base + q] = s;
                        }
                    }
                    __syncthreads();
                    // stage 2: H-slide, 9-tap along H (320 tasks, 8 outs each)
                    if (tid < 320) {
                        float c[16];
                        #pragma unroll
                        for (int q = 0; q < 16; ++q)
                            c[q] = wsum[ht_f][(ht_base + q) * WSTR + ht_w];
                        float s = c[0]+c[1]+c[2]+c[3]+c[4]+c[5]+c[6]+c[7]+c[8];
                        hcol[ht_f][ht_base * WSTR + ht_w] = s;
                        #pragma unroll
                        for (int q = 1; q < 8; ++q) {
                            s += c[q + 8] - c[q - 1];
                            hcol[ht_f][(ht_base + q) * WSTR + ht_w] = s;
                        }
                    }
                    __syncthreads();
                    // stage 3: ring + running sums (5 reads/thread)
                    #pragma unroll
                    for (int f = 0; f < 5; ++f) {
                        float P = hcol[f][hi * WSTR + wi];
                        R[f] += P - S[f][j];
                        S[f][j] = P;
                    }
                } else {
                    #pragma unroll
                    for (int f = 0; f < 5; ++f) { R[f] -= S[f][j]; S[f][j] = 0.f; }
                }
                if (k >= 8) {
                    float cross = R[4] - R[0] * R[1] * INV_WS;
                    float Iv    = R[2] - R[0] * R[0] * INV_WS;
                    float Jv    = R[3] - R[1] * R[1] * INV_WS;
                    local += cross * cross / (Iv * Jv + 1e-5f);
                }
            }
        }
    }

    // per-block partial: wave reduce -> LDS -> thread 0
    for (int off = 32; off; off >>= 1) local += __shfl_down(local, off);
    if ((tid & 63) == 0) s_p[tid >> 6] = (double)local;
    __syncthreads();
    if (tid == 0) {
        double b = 0.0;
        #pragma unroll
        for (int wv = 0; wv < 8; ++wv) b += s_p[wv];
        part[(blockIdx.z * gridDim.y + blockIdx.y) * gridDim.x + blockIdx.x] = b;
    }
}

// ---------------------------------------------------------------------------
// Gradient loss: float4 grid-stride (R4 structure, measured ~24 us).
// Per-block partial.
// ---------------------------------------------------------------------------
__global__ void grad_kernel(const float* __restrict__ s, double* __restrict__ part) {
    __shared__ double s_p[4];
    const int Q = NVOX / 4;                       // float4s per channel
    const float4* s4 = (const float4*)s;
    float local = 0.f;
    for (int q = blockIdx.x * 256 + threadIdx.x; q < Q; q += gridDim.x * 256) {
        int w4   = q % (DIM / 4);
        int rest = q / (DIM / 4);
        int h = rest % DIM;
        int d = rest / DIM;
        #pragma unroll
        for (int c = 0; c < 3; ++c) {
            const int qi = c * Q + q;
            float4 v = s4[qi];
            float t;
            t = v.y - v.x; local += t * t;
            t = v.z - v.y; local += t * t;
            t = v.w - v.z; local += t * t;
            if (w4 < DIM / 4 - 1) {
                float nx = s[c * NVOX + q * 4 + 4];
                t = nx - v.w; local += t * t;
            }
            if (h < DIM - 1) {
                float4 vh = s4[qi + DIM / 4];
                t = vh.x - v.x; local += t * t;
                t = vh.y - v.y; local += t * t;
                t = vh.z - v.z; local += t * t;
                t = vh.w - v.w; local += t * t;
            }
            if (d < DIM - 1) {
                float4 vd = s4[qi + PLANE / 4];
                t = vd.x - v.x; local += t * t;
                t = vd.y - v.y; local += t * t;
                t = vd.z - v.z; local += t * t;
                t = vd.w - v.w; local += t * t;
            }
        }
    }
    for (int off = 32; off; off >>= 1) local += __shfl_down(local, off);
    if ((threadIdx.x & 63) == 0) s_p[threadIdx.x >> 6] = (double)local;
    __syncthreads();
    if (threadIdx.x == 0) {
        part[NCC_PARTS + blockIdx.x] = s_p[0] + s_p[1] + s_p[2] + s_p[3];
    }
}

// ---------------------------------------------------------------------------
// Final combine: 1524 doubles -> 3 floats.
// ---------------------------------------------------------------------------
__global__ void final_kernel(const double* __restrict__ part, float* __restrict__ out) {
    __shared__ double s_n[4], s_g[4];
    double n = 0.0, g = 0.0;
    for (int i = threadIdx.x; i < NCC_PARTS; i += 256) n += part[i];
    for (int i = threadIdx.x; i < GRAD_PARTS; i += 256) g += part[NCC_PARTS + i];
    for (int off = 32; off; off >>= 1) {
        n += __shfl_down(n, off);
        g += __shfl_down(g, off);
    }
    if ((threadIdx.x & 63) == 0) {
        s_n[threadIdx.x >> 6] = n;
        s_g[threadIdx.x >> 6] = g;
    }
    __syncthreads();
    if (threadIdx.x == 0) {
        double ncc_sum  = s_n[0] + s_n[1] + s_n[2] + s_n[3];
        double grad_sum = s_g[0] + s_g[1] + s_g[2] + s_g[3];
        double ncc  = -(ncc_sum / 4096000.0);
        double grad = grad_sum / 36633600.0;   // sum / (3*159*160*160) / 3
        double loss = 10.0 * ncc + 15.0 * grad;
        out[0] = (float)loss;
        out[1] = (float)ncc;
        out[2] = (float)grad;
    }
}

extern "C" void kernel_launch(void* const* d_in, const int* in_sizes, int n_in,
                              void* d_out, int out_size, void* d_ws, size_t ws_size,
                              hipStream_t stream) {
    const float* y    = (const float*)d_in[0];
    const float* tgt  = (const float*)d_in[1];
    // d_in[2] = src, unused by the reference
    const float* flow = (const float*)d_in[3];
    float* out = (float*)d_out;
    double* part = (double*)d_ws;   // every slot written every call

    dim3 g1(DIM / TW, DIM / TH, DIM / DC);   // (5, 10, 10)
    ncc_kernel<<<g1, 512, 0, stream>>>(tgt, y, part);
    grad_kernel<<<GRAD_PARTS, 256, 0, stream>>>(flow, part);
    final_kernel<<<1, 256, 0, stream>>>(part, out);
}